// Round 1
// baseline (696.757 us; speedup 1.0000x reference)
//
#include <hip/hip_runtime.h>
#include <math.h>

// ---------------------------------------------------------------------------
// Chamfer distance via MFMA (gfx950).
//
// d2(p,g) = p^2 + g^2 - 2 p.g  is computed ENTIRELY inside
// v_mfma_f32_32x32x16_bf16 using a bf16 hi/lo (Dekker) split, K=16 slots:
//   k0-2 : phi . mhi        (m = -2g)
//   k3-5 : plo . mhi
//   k6-8 : phi . mlo
//   k9-10: p2hi*1 + p2lo*1
//   k11-12: 1*g2hi + 1*g2lo
//   k13-15: plo . mlo
// acc = (phi+plo).(mhi+mlo) + p2 + g2 ~= p^2+g^2-2p.g, |err| ~ 2^-18 * O(terms).
// Both row-mins (minP) and col-mins (minG) are reduced from the SAME tiles,
// so each of the 16384^2 pairs is evaluated exactly once (the old kernel did
// it twice). Last block (ticket) computes the weighted sums + final output:
// 2 dispatches total instead of 4.
// ---------------------------------------------------------------------------

constexpr int NPTS  = 16384;
constexpr int BLOCK = 256;                       // 4 waves

constexpr int ROWS_PER_BLOCK = 512;              // pred rows per block
constexpr int COLS_PER_BLOCK = 512;              // gt cols per block
constexpr int NBX = NPTS / ROWS_PER_BLOCK;       // 32
constexpr int NBY = NPTS / COLS_PER_BLOCK;       // 32
constexpr int NBLOCKS = NBX * NBY;               // 1024
constexpr int WAVES = BLOCK / 64;                // 4
constexpr int ROWS_PER_WAVE = ROWS_PER_BLOCK / WAVES;  // 128
constexpr int ATILES = ROWS_PER_WAVE / 32;       // 4
constexpr int BTILES = COLS_PER_BLOCK / 32;      // 16

typedef __attribute__((ext_vector_type(8)))  __bf16 bf16x8;
typedef __attribute__((ext_vector_type(16))) float  f32x16;

__device__ inline unsigned short f2bf(float f) {         // RNE float->bf16 bits
    unsigned u = __float_as_uint(f);
    u += 0x7FFFu + ((u >> 16) & 1u);
    return (unsigned short)(u >> 16);
}
__device__ inline float bf2f(unsigned short h) {
    return __uint_as_float(((unsigned)h) << 16);
}
__device__ inline __bf16 bfbits(unsigned short v) {
    return __builtin_bit_cast(__bf16, v);
}

// ---------------------------------------------------------------------------
// Pack: per point, 8 bf16 (16 B): [hx,hy,hz, lx,ly,lz, s_hi,s_lo]
// A-side: h/l = split(p), s = |p|^2.  B-side: h/l = split(-2g), s = |g|^2.
// Also inits minP/minG = +inf bits and ticket = 0 (no reliance on ws poison).
// ---------------------------------------------------------------------------
__global__ __launch_bounds__(BLOCK) void pack_init_kernel(
    const float* __restrict__ pred, const float* __restrict__ gt,
    uint4* __restrict__ Apk, uint4* __restrict__ Bpk,
    unsigned int* __restrict__ minP, unsigned int* __restrict__ minG,
    unsigned int* __restrict__ ticket)
{
    int i = blockIdx.x * BLOCK + threadIdx.x;
    if (i == 0) *ticket = 0u;
    if (i >= NPTS) return;

    {
        float x = pred[3*i], y = pred[3*i+1], z = pred[3*i+2];
        unsigned short hx = f2bf(x), hy = f2bf(y), hz = f2bf(z);
        unsigned short lx = f2bf(x - bf2f(hx));
        unsigned short ly = f2bf(y - bf2f(hy));
        unsigned short lz = f2bf(z - bf2f(hz));
        float p2 = fmaf(x, x, fmaf(y, y, z * z));
        unsigned short sh = f2bf(p2), sl = f2bf(p2 - bf2f(sh));
        uint4 w;
        w.x = (unsigned)hx | ((unsigned)hy << 16);
        w.y = (unsigned)hz | ((unsigned)lx << 16);
        w.z = (unsigned)ly | ((unsigned)lz << 16);
        w.w = (unsigned)sh | ((unsigned)sl << 16);
        Apk[i] = w;
    }
    {
        float gx = gt[3*i], gy = gt[3*i+1], gz = gt[3*i+2];
        float mx = -2.0f * gx, my = -2.0f * gy, mz = -2.0f * gz;
        unsigned short hx = f2bf(mx), hy = f2bf(my), hz = f2bf(mz);
        unsigned short lx = f2bf(mx - bf2f(hx));
        unsigned short ly = f2bf(my - bf2f(hy));
        unsigned short lz = f2bf(mz - bf2f(hz));
        float g2 = fmaf(gx, gx, fmaf(gy, gy, gz * gz));
        unsigned short sh = f2bf(g2), sl = f2bf(g2 - bf2f(sh));
        uint4 w;
        w.x = (unsigned)hx | ((unsigned)hy << 16);
        w.y = (unsigned)hz | ((unsigned)lx << 16);
        w.z = (unsigned)ly | ((unsigned)lz << 16);
        w.w = (unsigned)sh | ((unsigned)sl << 16);
        Bpk[i] = w;
    }
    minP[i] = 0x7F800000u;   // +inf
    minG[i] = 0x7F800000u;
}

// Build A fragment (8 bf16, k = 8*half + e; any consistent k-permutation is
// harmless since A and B use the same mapping).
__device__ inline bf16x8 frag_from_A(uint4 c, int half) {
    unsigned short e0 = (unsigned short)(c.x), e1 = (unsigned short)(c.x >> 16),
                   e2 = (unsigned short)(c.y), e3 = (unsigned short)(c.y >> 16),
                   e4 = (unsigned short)(c.z), e5 = (unsigned short)(c.z >> 16),
                   e6 = (unsigned short)(c.w), e7 = (unsigned short)(c.w >> 16);
    const unsigned short ONE = 0x3F80;   // bf16 1.0
    bf16x8 f;
    if (half == 0) {  // k0..7 = phx,phy,phz, plx,ply,plz, phx,phy
        f[0]=bfbits(e0); f[1]=bfbits(e1); f[2]=bfbits(e2); f[3]=bfbits(e3);
        f[4]=bfbits(e4); f[5]=bfbits(e5); f[6]=bfbits(e0); f[7]=bfbits(e1);
    } else {          // k8..15 = phz, p2h, p2l, 1, 1, plx, ply, plz
        f[0]=bfbits(e2); f[1]=bfbits(e6); f[2]=bfbits(e7); f[3]=bfbits(ONE);
        f[4]=bfbits(ONE); f[5]=bfbits(e3); f[6]=bfbits(e4); f[7]=bfbits(e5);
    }
    return f;
}
__device__ inline bf16x8 frag_from_B(uint4 c, int half) {
    unsigned short e0 = (unsigned short)(c.x), e1 = (unsigned short)(c.x >> 16),
                   e2 = (unsigned short)(c.y), e3 = (unsigned short)(c.y >> 16),
                   e4 = (unsigned short)(c.z), e5 = (unsigned short)(c.z >> 16),
                   e6 = (unsigned short)(c.w), e7 = (unsigned short)(c.w >> 16);
    const unsigned short ONE = 0x3F80;
    bf16x8 f;
    if (half == 0) {  // k0..7 = mhx,mhy,mhz, mhx,mhy,mhz, mlx,mly
        f[0]=bfbits(e0); f[1]=bfbits(e1); f[2]=bfbits(e2); f[3]=bfbits(e0);
        f[4]=bfbits(e1); f[5]=bfbits(e2); f[6]=bfbits(e3); f[7]=bfbits(e4);
    } else {          // k8..15 = mlz, 1, 1, g2h, g2l, mlx, mly, mlz
        f[0]=bfbits(e5); f[1]=bfbits(ONE); f[2]=bfbits(ONE); f[3]=bfbits(e6);
        f[4]=bfbits(e7); f[5]=bfbits(e3); f[6]=bfbits(e4); f[7]=bfbits(e5);
    }
    return f;
}

__device__ inline float tree16(const f32x16 a) {   // min of 16 via v_min3 tree
    float m0 = fminf(fminf(a[0],  a[1]),  a[2]);
    float m1 = fminf(fminf(a[3],  a[4]),  a[5]);
    float m2 = fminf(fminf(a[6],  a[7]),  a[8]);
    float m3 = fminf(fminf(a[9],  a[10]), a[11]);
    float m4 = fminf(fminf(a[12], a[13]), a[14]);
    float m5 = fminf(fminf(m0, m1), m2);
    float m6 = fminf(fminf(m3, m4), a[15]);
    return fminf(m5, m6);
}

// ---------------------------------------------------------------------------
// Main kernel: grid (32,32); block = 512 rows x 512 cols super-tile.
// Wave w owns rows [w*128, w*128+128). B fragments register-resident (16).
// C/D layout (HW-verified m74/m101): col = lane&31,
// row = (reg&3) + 8*(reg>>2) + 4*(lane>>5).
// ---------------------------------------------------------------------------
__global__ __launch_bounds__(BLOCK, 2) void chamfer_mfma_kernel(
    const uint4* __restrict__ Apk, const uint4* __restrict__ Bpk,
    unsigned int* __restrict__ minP, unsigned int* __restrict__ minG,
    const float* __restrict__ wpred, const float* __restrict__ wgt,
    unsigned int* __restrict__ ticket, float* __restrict__ out)
{
    const int tid  = threadIdx.x;
    const int wv   = tid >> 6;
    const int lane = tid & 63;
    const int half = lane >> 5;
    const int ln31 = lane & 31;

    const int rowBase = blockIdx.x * ROWS_PER_BLOCK + wv * ROWS_PER_WAVE;
    const int colBase = blockIdx.y * COLS_PER_BLOCK;

    // B fragments: one 16B compact row per lane-col, kept in registers.
    bf16x8 B[BTILES];
    #pragma unroll
    for (int bt = 0; bt < BTILES; ++bt) {
        uint4 c = Bpk[colBase + bt * 32 + ln31];
        B[bt] = frag_from_B(c, half);
    }
    // Prefetch A compact rows.
    uint4 Ac[ATILES];
    #pragma unroll
    for (int a = 0; a < ATILES; ++a)
        Ac[a] = Apk[rowBase + a * 32 + ln31];

    const f32x16 zacc = {0.f,0.f,0.f,0.f, 0.f,0.f,0.f,0.f,
                         0.f,0.f,0.f,0.f, 0.f,0.f,0.f,0.f};

    float colacc[BTILES];
    #pragma unroll
    for (int bt = 0; bt < BTILES; ++bt) colacc[bt] = INFINITY;

    #pragma unroll
    for (int a = 0; a < ATILES; ++a) {
        bf16x8 af = frag_from_A(Ac[a], half);
        float rm[16];
        #pragma unroll
        for (int r = 0; r < 16; ++r) rm[r] = INFINITY;

        #pragma unroll
        for (int bt = 0; bt < BTILES; bt += 2) {
            f32x16 acc0 = __builtin_amdgcn_mfma_f32_32x32x16_bf16(af, B[bt],     zacc, 0, 0, 0);
            f32x16 acc1 = __builtin_amdgcn_mfma_f32_32x32x16_bf16(af, B[bt + 1], zacc, 0, 0, 0);
            #pragma unroll
            for (int r = 0; r < 16; ++r)
                rm[r] = fminf(rm[r], fminf(acc0[r], acc1[r]));   // v_min3
            colacc[bt]     = fminf(colacc[bt],     tree16(acc0));
            colacc[bt + 1] = fminf(colacc[bt + 1], tree16(acc1));
        }

        // Finish rows: butterfly min over the 32-lane col dimension.
        #pragma unroll
        for (int s = 1; s < 32; s <<= 1) {
            #pragma unroll
            for (int r = 0; r < 16; ++r)
                rm[r] = fminf(rm[r], __shfl_xor(rm[r], s, 64));
        }
        const int rb = rowBase + a * 32 + 4 * half;
        #pragma unroll
        for (int r = 0; r < 16; ++r) {
            if (ln31 == r)
                atomicMin(&minP[rb + (r & 3) + 8 * (r >> 2)],
                          __float_as_uint(rm[r]));
        }
    }

    // Cols: combine halves (rows differ by lane>>5), then across waves in LDS.
    #pragma unroll
    for (int bt = 0; bt < BTILES; ++bt)
        colacc[bt] = fminf(colacc[bt], __shfl_xor(colacc[bt], 32, 64));

    __shared__ float cmin[WAVES][COLS_PER_BLOCK];
    if (half == 0) {
        #pragma unroll
        for (int bt = 0; bt < BTILES; ++bt)
            cmin[wv][bt * 32 + ln31] = colacc[bt];
    }
    __syncthreads();
    for (int c = tid; c < COLS_PER_BLOCK; c += BLOCK) {
        float v = fminf(fminf(cmin[0][c], cmin[1][c]),
                        fminf(cmin[2][c], cmin[3][c]));
        atomicMin(&minG[colBase + c], __float_as_uint(v));
    }

    // ------------------- ticket: last block finalizes -----------------------
    __shared__ unsigned int sTicket;
    __syncthreads();            // barrier drains vmcnt: all our atomics done
    __threadfence();
    if (tid == 0) sTicket = atomicAdd(ticket, 1u);
    __syncthreads();
    if (sTicket != (unsigned)(NBLOCKS - 1)) return;
    __threadfence();

    // All blocks' atomicMins complete. Read via identity atomics (coherent),
    // clamp >=0 (clamp commutes with min), weighted sums.
    float np = 0.f, dp = 0.f, ng = 0.f, dg = 0.f;
    for (int i = tid; i < NPTS; i += BLOCK) {
        float v = fmaxf(__uint_as_float(atomicMin(&minP[i], 0xFFFFFFFFu)), 0.0f);
        float w = wpred[i];
        np = fmaf(w, v, np); dp += w;
        float u = fmaxf(__uint_as_float(atomicMin(&minG[i], 0xFFFFFFFFu)), 0.0f);
        float x = wgt[i];
        ng = fmaf(x, u, ng); dg += x;
    }
    #pragma unroll
    for (int off = 1; off < 64; off <<= 1) {
        np += __shfl_xor(np, off, 64);
        dp += __shfl_xor(dp, off, 64);
        ng += __shfl_xor(ng, off, 64);
        dg += __shfl_xor(dg, off, 64);
    }
    __shared__ float sred[4][WAVES];
    if (lane == 0) { sred[0][wv] = np; sred[1][wv] = dp;
                     sred[2][wv] = ng; sred[3][wv] = dg; }
    __syncthreads();
    if (tid == 0) {
        float NP = 0.f, DP = 0.f, NG = 0.f, DG = 0.f;
        #pragma unroll
        for (int k = 0; k < WAVES; ++k) {
            NP += sred[0][k]; DP += sred[1][k];
            NG += sred[2][k]; DG += sred[3][k];
        }
        out[0] = NP / fmaxf(DP, 1e-9f) + NG / fmaxf(DG, 1e-9f);
    }
}

// ---------------------------------------------------------------------------
extern "C" void kernel_launch(void* const* d_in, const int* in_sizes, int n_in,
                              void* d_out, int out_size, void* d_ws, size_t ws_size,
                              hipStream_t stream)
{
    const float* pred  = (const float*)d_in[0];   // (P,3)
    const float* gt    = (const float*)d_in[1];   // (G,3)
    const float* wpred = (const float*)d_in[2];   // (P,)
    const float* wgt   = (const float*)d_in[3];   // (G,)
    float* out = (float*)d_out;

    // ws layout: Apk(256K) | Bpk(256K) | minP(64K) | minG(64K) | ticket(4B)
    uint4* Apk = (uint4*)d_ws;
    uint4* Bpk = Apk + NPTS;
    unsigned int* minP = (unsigned int*)(Bpk + NPTS);
    unsigned int* minG = minP + NPTS;
    unsigned int* ticket = minG + NPTS;

    pack_init_kernel<<<NPTS / BLOCK, BLOCK, 0, stream>>>(
        pred, gt, Apk, Bpk, minP, minG, ticket);

    chamfer_mfma_kernel<<<dim3(NBX, NBY), BLOCK, 0, stream>>>(
        Apk, Bpk, minP, minG, wpred, wgt, ticket, out);
}

// Round 2
// 168.963 us; speedup vs baseline: 4.1237x; 4.1237x over previous
//
#include <hip/hip_runtime.h>
#include <math.h>

// ---------------------------------------------------------------------------
// Chamfer distance via MFMA (gfx950) — spill-free restructure of round 1.
//
// d2(p,g) = p^2 + g^2 - 2 p.g computed entirely inside
// v_mfma_f32_32x32x16_bf16 via bf16 hi/lo (Dekker) split over K=16 slots
// (verified absmax 0.0 in round 1). Round 1 spilled ~1.6 GB of scratch
// (B[16] register-resident frags + 4x rm state squeezed the arch-VGPR class);
// this version keeps ~80 live VGPRs: B frags streamed from global in a
// frag-ready layout (one dwordx4 = one fragment, no perms), one A-tile of
// row-state at a time, col-mins via LDS atomics.
// ---------------------------------------------------------------------------

constexpr int NPTS  = 16384;
constexpr int BLOCK = 256;                        // 4 waves
constexpr int WAVES = BLOCK / 64;

constexpr int ROWS_PER_BLOCK = 512;
constexpr int COLS_PER_BLOCK = 512;
constexpr int NBX = NPTS / ROWS_PER_BLOCK;        // 32
constexpr int NBY = NPTS / COLS_PER_BLOCK;        // 32
constexpr int NBLOCKS = NBX * NBY;                // 1024
constexpr int ROWS_PER_WAVE = ROWS_PER_BLOCK / WAVES;   // 128
constexpr int ATILES = ROWS_PER_WAVE / 32;        // 4
constexpr int CSTEPS = COLS_PER_BLOCK / 64;       // 8 (two 32-col tiles/step)

typedef __attribute__((ext_vector_type(8)))  __bf16 bf16x8;
typedef __attribute__((ext_vector_type(16))) float  f32x16;

__device__ inline unsigned short f2bf(float f) {          // RNE float->bf16
    unsigned u = __float_as_uint(f);
    u += 0x7FFFu + ((u >> 16) & 1u);
    return (unsigned short)(u >> 16);
}
__device__ inline float bf2f(unsigned short h) {
    return __uint_as_float(((unsigned)h) << 16);
}
__device__ inline unsigned pk(unsigned short lo, unsigned short hi) {
    return (unsigned)lo | ((unsigned)hi << 16);
}

// ---------------------------------------------------------------------------
// Pack to FRAG-READY layout: for each point, two uint4s (one per k-half),
// each being the exact 8-bf16 MFMA fragment for that half. Layout matches
// round 1's frag_from_A/frag_from_B (HW-verified, absmax 0.0):
//   A half0: [phx,phy,phz, plx,ply,plz, phx,phy]
//   A half1: [phz, p2h, p2l, 1, 1, plx, ply, plz]
//   B half0: [mhx,mhy,mhz, mhx,mhy,mhz, mlx,mly]      (m = -2g)
//   B half1: [mlz, 1, 1, g2h, g2l, mlx, mly, mlz]
// Array layout: half-major — Xf[half*NPTS + i].
// ---------------------------------------------------------------------------
__global__ __launch_bounds__(BLOCK) void pack_init_kernel(
    const float* __restrict__ pred, const float* __restrict__ gt,
    uint4* __restrict__ Af, uint4* __restrict__ Bf,
    unsigned int* __restrict__ minP, unsigned int* __restrict__ minG,
    unsigned int* __restrict__ ticket)
{
    const unsigned short ONE = 0x3F80;
    int i = blockIdx.x * BLOCK + threadIdx.x;
    if (i == 0) *ticket = 0u;
    if (i >= NPTS) return;

    {   // A side (pred)
        float x = pred[3*i], y = pred[3*i+1], z = pred[3*i+2];
        unsigned short hx = f2bf(x), hy = f2bf(y), hz = f2bf(z);
        unsigned short lx = f2bf(x - bf2f(hx));
        unsigned short ly = f2bf(y - bf2f(hy));
        unsigned short lz = f2bf(z - bf2f(hz));
        float p2 = fmaf(x, x, fmaf(y, y, z * z));
        unsigned short sh = f2bf(p2), sl = f2bf(p2 - bf2f(sh));
        uint4 h0, h1;
        h0.x = pk(hx, hy); h0.y = pk(hz, lx); h0.z = pk(ly, lz); h0.w = pk(hx, hy);
        h1.x = pk(hz, sh); h1.y = pk(sl, ONE); h1.z = pk(ONE, lx); h1.w = pk(ly, lz);
        Af[i] = h0;
        Af[NPTS + i] = h1;
    }
    {   // B side (gt, pre-scaled by -2)
        float gx = gt[3*i], gy = gt[3*i+1], gz = gt[3*i+2];
        float mx = -2.0f * gx, my = -2.0f * gy, mz = -2.0f * gz;
        unsigned short hx = f2bf(mx), hy = f2bf(my), hz = f2bf(mz);
        unsigned short lx = f2bf(mx - bf2f(hx));
        unsigned short ly = f2bf(my - bf2f(hy));
        unsigned short lz = f2bf(mz - bf2f(hz));
        float g2 = fmaf(gx, gx, fmaf(gy, gy, gz * gz));
        unsigned short sh = f2bf(g2), sl = f2bf(g2 - bf2f(sh));
        uint4 h0, h1;
        h0.x = pk(hx, hy); h0.y = pk(hz, hx); h0.z = pk(hy, hz); h0.w = pk(lx, ly);
        h1.x = pk(lz, ONE); h1.y = pk(ONE, sh); h1.z = pk(sl, lx); h1.w = pk(ly, lz);
        Bf[i] = h0;
        Bf[NPTS + i] = h1;
    }
    minP[i] = 0x7F800000u;   // +inf
    minG[i] = 0x7F800000u;
}

__device__ inline float tree16(const f32x16 a) {   // min of 16 (v_min3 tree)
    float m0 = fminf(fminf(a[0],  a[1]),  a[2]);
    float m1 = fminf(fminf(a[3],  a[4]),  a[5]);
    float m2 = fminf(fminf(a[6],  a[7]),  a[8]);
    float m3 = fminf(fminf(a[9],  a[10]), a[11]);
    float m4 = fminf(fminf(a[12], a[13]), a[14]);
    float m5 = fminf(fminf(m0, m1), m2);
    float m6 = fminf(fminf(m3, m4), a[15]);
    return fminf(m5, m6);
}

// ---------------------------------------------------------------------------
// Main kernel: grid (32,32); block tile 512 rows x 512 cols, 4 waves.
// Wave w owns rows [w*128, w*128+128), one 32-row A-tile at a time.
// C/D layout (HW-verified): col = lane&31, row = (reg&3)+8*(reg>>2)+4*(lane>>5).
// Col-mins -> LDS atomicMin (block scope) -> one global atomicMin per col.
// Last block (ticket) computes weighted sums + writes out[0].
// ---------------------------------------------------------------------------
__global__ __launch_bounds__(BLOCK, 2) void chamfer_mfma_kernel(
    const uint4* __restrict__ Af, const uint4* __restrict__ Bf,
    unsigned int* __restrict__ minP, unsigned int* __restrict__ minG,
    const float* __restrict__ wpred, const float* __restrict__ wgt,
    unsigned int* __restrict__ ticket, float* __restrict__ out)
{
    const int tid  = threadIdx.x;
    const int wv   = tid >> 6;
    const int lane = tid & 63;
    const int half = lane >> 5;
    const int ln31 = lane & 31;

    const int rowBase = blockIdx.x * ROWS_PER_BLOCK + wv * ROWS_PER_WAVE;
    const int colBase = blockIdx.y * COLS_PER_BLOCK;

    __shared__ unsigned int cminS[COLS_PER_BLOCK];
    for (int c = tid; c < COLS_PER_BLOCK; c += BLOCK)
        cminS[c] = 0x7F800000u;
    __syncthreads();

    // Per-half base pointers; a fragment is exactly one uint4.
    const uint4* __restrict__ Ah = Af + half * NPTS;
    const uint4* __restrict__ Bh = Bf + half * NPTS + colBase;

    const f32x16 zacc = {0.f,0.f,0.f,0.f, 0.f,0.f,0.f,0.f,
                         0.f,0.f,0.f,0.f, 0.f,0.f,0.f,0.f};

    #pragma unroll 1
    for (int a = 0; a < ATILES; ++a) {
        uint4 ac = Ah[rowBase + a * 32 + ln31];
        bf16x8 af = __builtin_bit_cast(bf16x8, ac);

        float rm[16];
        #pragma unroll
        for (int r = 0; r < 16; ++r) rm[r] = INFINITY;

        #pragma unroll 2
        for (int s = 0; s < CSTEPS; ++s) {
            bf16x8 b0 = __builtin_bit_cast(bf16x8, Bh[s * 64 + ln31]);
            bf16x8 b1 = __builtin_bit_cast(bf16x8, Bh[s * 64 + 32 + ln31]);
            f32x16 acc0 = __builtin_amdgcn_mfma_f32_32x32x16_bf16(af, b0, zacc, 0, 0, 0);
            f32x16 acc1 = __builtin_amdgcn_mfma_f32_32x32x16_bf16(af, b1, zacc, 0, 0, 0);
            #pragma unroll
            for (int r = 0; r < 16; ++r)
                rm[r] = fminf(rm[r], fminf(acc0[r], acc1[r]));   // v_min3
            // Column mins for this A-tile: tree over 16 rows, combine halves.
            float c0 = fmaxf(tree16(acc0), 0.0f);
            float c1 = fmaxf(tree16(acc1), 0.0f);
            c0 = fminf(c0, __shfl_xor(c0, 32, 64));
            c1 = fminf(c1, __shfl_xor(c1, 32, 64));
            if (half == 0) {
                atomicMin(&cminS[s * 64 + ln31],      __float_as_uint(c0));
                atomicMin(&cminS[s * 64 + 32 + ln31], __float_as_uint(c1));
            }
        }

        // Row mins: butterfly over the 32 col-lanes.
        #pragma unroll
        for (int s = 1; s < 32; s <<= 1) {
            #pragma unroll
            for (int r = 0; r < 16; ++r)
                rm[r] = fminf(rm[r], __shfl_xor(rm[r], s, 64));
        }
        const int rb = rowBase + a * 32 + 4 * half;
        #pragma unroll
        for (int r = 0; r < 16; ++r) {
            if (ln31 == r)
                atomicMin(&minP[rb + (r & 3) + 8 * (r >> 2)],
                          __float_as_uint(fmaxf(rm[r], 0.0f)));
        }
    }

    __syncthreads();
    for (int c = tid; c < COLS_PER_BLOCK; c += BLOCK)
        atomicMin(&minG[colBase + c], cminS[c]);   // already clamped >= 0

    // ------------------- ticket: last block finalizes -----------------------
    __shared__ unsigned int sTicket;
    __syncthreads();            // our atomics are issued; fence orders them
    __threadfence();
    if (tid == 0) sTicket = atomicAdd(ticket, 1u);
    __syncthreads();
    if (sTicket != (unsigned)(NBLOCKS - 1)) return;
    __threadfence();

    // Read via identity atomics (coherent across XCDs), weighted sums.
    float np = 0.f, dp = 0.f, ng = 0.f, dg = 0.f;
    for (int i = tid; i < NPTS; i += BLOCK) {
        float v = __uint_as_float(atomicMin(&minP[i], 0xFFFFFFFFu));
        float w = wpred[i];
        np = fmaf(w, v, np); dp += w;
        float u = __uint_as_float(atomicMin(&minG[i], 0xFFFFFFFFu));
        float x = wgt[i];
        ng = fmaf(x, u, ng); dg += x;
    }
    #pragma unroll
    for (int off = 1; off < 64; off <<= 1) {
        np += __shfl_xor(np, off, 64);
        dp += __shfl_xor(dp, off, 64);
        ng += __shfl_xor(ng, off, 64);
        dg += __shfl_xor(dg, off, 64);
    }
    __shared__ float sred[4][WAVES];
    if (lane == 0) { sred[0][wv] = np; sred[1][wv] = dp;
                     sred[2][wv] = ng; sred[3][wv] = dg; }
    __syncthreads();
    if (tid == 0) {
        float NP = 0.f, DP = 0.f, NG = 0.f, DG = 0.f;
        #pragma unroll
        for (int k = 0; k < WAVES; ++k) {
            NP += sred[0][k]; DP += sred[1][k];
            NG += sred[2][k]; DG += sred[3][k];
        }
        out[0] = NP / fmaxf(DP, 1e-9f) + NG / fmaxf(DG, 1e-9f);
    }
}

// ---------------------------------------------------------------------------
extern "C" void kernel_launch(void* const* d_in, const int* in_sizes, int n_in,
                              void* d_out, int out_size, void* d_ws, size_t ws_size,
                              hipStream_t stream)
{
    const float* pred  = (const float*)d_in[0];   // (P,3)
    const float* gt    = (const float*)d_in[1];   // (G,3)
    const float* wpred = (const float*)d_in[2];   // (P,)
    const float* wgt   = (const float*)d_in[3];   // (G,)
    float* out = (float*)d_out;

    // ws: Af(512K) | Bf(512K) | minP(64K) | minG(64K) | ticket  (~1.13 MB)
    uint4* Af = (uint4*)d_ws;
    uint4* Bf = Af + 2 * NPTS;
    unsigned int* minP = (unsigned int*)(Bf + 2 * NPTS);
    unsigned int* minG = minP + NPTS;
    unsigned int* ticket = minG + NPTS;

    pack_init_kernel<<<NPTS / BLOCK, BLOCK, 0, stream>>>(
        pred, gt, Af, Bf, minP, minG, ticket);

    chamfer_mfma_kernel<<<dim3(NBX, NBY), BLOCK, 0, stream>>>(
        Af, Bf, minP, minG, wpred, wgt, ticket, out);
}